// Round 7
// baseline (233.845 us; speedup 1.0000x reference)
//
#include <hip/hip_runtime.h>
#include <hip/hip_cooperative_groups.h>
#include <stdint.h>

namespace cg = cooperative_groups;

// Problem constants (match reference)
#define N_PRIORS 2097152
#define KTOP 512
#define NBINS 2048
#define GBLK 256                 // cooperative grid: 1 block per CU
#define SCAP 64                  // stash slots per block (mean 3.1, Poisson-safe)
#define SELCAP 2048
#define SSTASH 0.9915f           // stash pre-filter; expected ~800 >= 512 (10 sigma)

// ws layout: [0, 1K) u32 blk_cnt[256]; [1K, 1K+128K) u64 stash[256*64]

__device__ __forceinline__ uint64_t pack_key(float s, int idx) {
    // descending score, ascending index tie-break (== stable top_k)
    return ((uint64_t)__float_as_uint(s) << 32) | (uint32_t)(~idx);
}

__device__ __forceinline__ float score_of(float c0, float c1) {
    #pragma clang fp contract(off)
    float m  = fmaxf(c0, c1);
    float e0 = expf(c0 - m);
    float e1 = expf(c1 - m);
    return e1 / (e0 + e1);
}

__device__ __forceinline__ int bin_of(float s) {
    #pragma clang fp contract(off)
    int b = (int)((s - 0.9f) * 20480.0f);   // 2048 bins over (0.9, 1.0]
    return b > (NBINS - 1) ? (NBINS - 1) : b;
}

// next kept index > i from 16 LDS u32 words (uniform across threads)
__device__ __forceinline__ int next_kept(const uint32_t* kw, int i) {
    int w = (i + 1) >> 5, b = (i + 1) & 31;
    if (w >= 16) return KTOP;
    uint32_t m = kw[w] & (0xFFFFFFFFu << b);
    while (m == 0u) { ++w; if (w >= 16) return KTOP; m = kw[w]; }
    return w * 32 + __builtin_ctz(m);
}

__launch_bounds__(1024)
__global__ void fused(const float4* __restrict__ loc,
                      const float4* __restrict__ priors,
                      const float4* __restrict__ conf4,
                      uint32_t* __restrict__ blk_cnt,
                      uint64_t* __restrict__ stash,
                      float* __restrict__ out) {
    #pragma clang fp contract(off)
    __shared__ uint64_t sel[SELCAP];        // 16 KB
    __shared__ uint32_t hist[NBINS];        // 8 KB (fallback only)
    __shared__ float4 bpk[KTOP];            // 8 KB pixel boxes
    __shared__ float  sar[KTOP], ssc[KTOP]; // 4 KB
    __shared__ uint32_t kw32[16];           // keep bits
    __shared__ uint32_t nselS, fbS, lcnt;
    __shared__ int bmaxS;

    int tid = threadIdx.x;          // 1024 threads
    int blk = blockIdx.x;           // 256 blocks
    int lane = tid & 63, wv = tid >> 6;

    // ================= Phase A (all blocks): stream conf, stash =============
    if (tid == 0) lcnt = 0u;
    __syncthreads();
    uint64_t* reg = stash + (size_t)blk * SCAP;
    #pragma unroll
    for (int i = 0; i < 4; ++i) {
        int f4i = blk * 4096 + i * 1024 + tid;
        float4 c = conf4[f4i];
        float s0 = score_of(c.x, c.y);
        float s1 = score_of(c.z, c.w);
        if (s0 > SSTASH) {
            uint32_t p = atomicAdd(&lcnt, 1u);
            if (p < SCAP) reg[p] = pack_key(s0, f4i * 2);
        }
        if (s1 > SSTASH) {
            uint32_t p = atomicAdd(&lcnt, 1u);
            if (p < SCAP) reg[p] = pack_key(s1, f4i * 2 + 1);
        }
    }
    __syncthreads();
    if (tid == 0) blk_cnt[blk] = (lcnt <= SCAP) ? lcnt : 0xFFFFFFFFu;

    cg::this_grid().sync();
    if (blk != 0) return;

    // ================= Phase B (block 0 only) ===============================
    if (tid == 0) { nselS = 0u; fbS = 0u; bmaxS = 0; }
    __syncthreads();

    // ---- gather stash entries (~800 expected) ----
    if (tid < GBLK) {
        uint32_t c = blk_cnt[tid];
        if (c == 0xFFFFFFFFu) { atomicOr(&fbS, 1u); c = 0; }
        const uint64_t* regp = stash + (size_t)tid * SCAP;
        for (uint32_t j = 0; j < c; ++j) {
            uint64_t k = regp[j];
            uint32_t p = atomicAdd(&nselS, 1u);
            if (p < SELCAP) sel[p] = k; else atomicOr(&fbS, 1u);
        }
    }
    __syncthreads();
    uint32_t n = nselS;
    bool fb = (fbS != 0u) || (n < KTOP) || (n > SELCAP);
    __syncthreads();

    if (fb) {
        // ---- exact fallback: 2-pass histogram select over all of conf ----
        if (tid == 0) nselS = 0u;
        for (int b = tid; b < NBINS; b += 1024) hist[b] = 0u;
        __syncthreads();
        for (int f = tid; f < N_PRIORS / 2; f += 1024) {
            float4 c = conf4[f];
            float s0 = score_of(c.x, c.y);
            float s1 = score_of(c.z, c.w);
            if (s0 > 0.9f) atomicAdd(&hist[bin_of(s0)], 1u);
            if (s1 > 0.9f) atomicAdd(&hist[bin_of(s1)], 1u);
        }
        __syncthreads();
        for (int off = 1; off < NBINS; off <<= 1) {
            int b0 = tid, b1 = tid + 1024;
            uint32_t v0 = hist[b0] + ((b0 + off < NBINS) ? hist[b0 + off] : 0u);
            uint32_t v1 = hist[b1] + ((b1 + off < NBINS) ? hist[b1 + off] : 0u);
            __syncthreads();
            hist[b0] = v0; hist[b1] = v1;
            __syncthreads();
        }
        if (hist[tid] >= KTOP) atomicMax(&bmaxS, tid);
        if (hist[tid + 1024] >= KTOP) atomicMax(&bmaxS, tid + 1024);
        __syncthreads();
        int B = bmaxS;
        for (int f = tid; f < N_PRIORS / 2; f += 1024) {
            float4 c = conf4[f];
            float s0 = score_of(c.x, c.y);
            float s1 = score_of(c.z, c.w);
            if (s0 > 0.9f && bin_of(s0) >= B) {
                uint32_t p = atomicAdd(&nselS, 1u);
                if (p < SELCAP) sel[p] = pack_key(s0, 2 * f);
            }
            if (s1 > 0.9f && bin_of(s1) >= B) {
                uint32_t p = atomicAdd(&nselS, 1u);
                if (p < SELCAP) sel[p] = pack_key(s1, 2 * f + 1);
            }
        }
        __syncthreads();
        n = nselS; if (n > SELCAP) n = SELCAP;
        __syncthreads();
    }

    int P = KTOP; while (P < (int)n) P <<= 1;
    for (int t = tid; t < P; t += 1024) if (t >= (int)n) sel[t] = 0ull;
    __syncthreads();

    // ---- bitonic sort, descending (0-padding sinks) ----
    for (int k = 2; k <= P; k <<= 1) {
        for (int j = k >> 1; j > 0; j >>= 1) {
            for (int t = tid; t < P; t += 1024) {
                int ixj = t ^ j;
                if (ixj > t) {
                    uint64_t a = sel[t], b = sel[ixj];
                    bool sw = ((t & k) == 0) ? (a < b) : (a > b);
                    if (sw) { sel[t] = b; sel[ixj] = a; }
                }
            }
            __syncthreads();
        }
    }

    // ---- decode top-512 (exact numpy op order); keep bits via ballot ----
    {
        uint64_t key = (tid < KTOP) ? sel[tid] : 0ull;
        if (tid < KTOP) {
            float4 bb; float area, sc;
            if (key != 0ull) {
                sc = __uint_as_float((uint32_t)(key >> 32));
                int idx  = (int)(~(uint32_t)key);
                float4 l = loc[idx];
                float4 p = priors[idx];
                float cx = p.x + (l.x * 0.1f) * p.z;
                float cy = p.y + (l.y * 0.1f) * p.w;
                float w  = p.z * expf(l.z * 0.2f);
                float h  = p.w * expf(l.w * 0.2f);
                float x1 = cx - w * 0.5f;
                float y1 = cy - h * 0.5f;
                float x2 = x1 + w;
                float y2 = y1 + h;
                x1 *= 2048.0f; y1 *= 2048.0f; x2 *= 2048.0f; y2 *= 2048.0f;
                bb = make_float4(x1, y1, x2, y2);
                area = (x2 - x1 + 1.0f) * (y2 - y1 + 1.0f);
            } else {
                bb = make_float4(0.f, 0.f, 0.f, 0.f); area = 1.f; sc = 0.f;
            }
            bpk[tid] = bb; sar[tid] = area; ssc[tid] = sc;
        }
        uint64_t vb = __ballot(key != 0ull);    // wave w covers indices 64w..64w+63
        if (lane == 0 && wv < 8) {
            kw32[2 * wv]     = (uint32_t)vb;
            kw32[2 * wv + 1] = (uint32_t)(vb >> 32);
        }
    }
    __syncthreads();

    // ---- lazy greedy NMS: per actually-kept row i, 512 threads compute the
    //      row's IoUs in parallel and clear keep bits; 2 barriers/step, steps
    //      = #kept (~10-30 with dense-overlap random boxes) ----
    {
        int i = next_kept(kw32, -1);
        while (i < KTOP) {
            float4 rb = bpk[i];     // uniform broadcast
            float ra = sar[i];
            if (tid > i && tid < KTOP && ((kw32[tid >> 5] >> (tid & 31)) & 1u)) {
                float4 cb = bpk[tid];
                float xx1 = fmaxf(rb.x, cb.x);
                float yy1 = fmaxf(rb.y, cb.y);
                float xx2 = fminf(rb.z, cb.z);
                float yy2 = fminf(rb.w, cb.w);
                float ww = fmaxf(xx2 - xx1 + 1.0f, 0.0f);
                float hh = fmaxf(yy2 - yy1 + 1.0f, 0.0f);
                float inter = ww * hh;
                float iou = inter / (ra + sar[tid] - inter);
                if (iou > 0.4f) atomicAnd(&kw32[tid >> 5], ~(1u << (tid & 31)));
            }
            __syncthreads();                  // clears visible
            int ni = next_kept(kw32, i);      // uniform result
            __syncthreads();                  // all done reading before next clears
            i = ni;
        }
    }

    // ---- epilogue: [512,5], boxes /2048 (exact pow2), zeros if suppressed ----
    if (tid < KTOP) {
        const float inv = 1.0f / 2048.0f;
        int kb = (int)((kw32[tid >> 5] >> (tid & 31)) & 1u);
        float4 bb = bpk[tid];
        float* o = out + tid * 5;
        if (kb) {
            o[0] = bb.x * inv;
            o[1] = bb.y * inv;
            o[2] = bb.z * inv;
            o[3] = bb.w * inv;
            o[4] = ssc[tid];
        } else {
            o[0] = 0.f; o[1] = 0.f; o[2] = 0.f; o[3] = 0.f; o[4] = 0.f;
        }
    }
}

extern "C" void kernel_launch(void* const* d_in, const int* in_sizes, int n_in,
                              void* d_out, int out_size, void* d_ws, size_t ws_size,
                              hipStream_t stream) {
    const float4* loc4  = (const float4*)d_in[0];   // [1,N,4]
    const float4* conf4 = (const float4*)d_in[1];   // [1,N,2] as float4 pairs
    const float4* pri4  = (const float4*)d_in[2];   // [N,4]
    float* outp = (float*)d_out;                    // [512,5]

    uint8_t* ws = (uint8_t*)d_ws;
    uint32_t* blk_cnt = (uint32_t*)ws;              // 1 KB
    uint64_t* stash   = (uint64_t*)(ws + 1024);     // 128 KB

    void* args[] = { (void*)&loc4, (void*)&pri4, (void*)&conf4,
                     (void*)&blk_cnt, (void*)&stash, (void*)&outp };
    hipLaunchCooperativeKernel(reinterpret_cast<void*>(fused),
                               dim3(GBLK), dim3(1024), args, 0, stream);
}

// Round 8
// 208.739 us; speedup vs baseline: 1.1203x; 1.1203x over previous
//
#include <hip/hip_runtime.h>
#include <hip/hip_cooperative_groups.h>
#include <stdint.h>

namespace cg = cooperative_groups;

// Problem constants (match reference)
#define N_PRIORS 2097152
#define KTOP 512
#define NBINS 2048
#define GBLK 256                 // cooperative grid: 1 block per CU
#define SCAP 64                  // stash slots per block (mean 3.1, Poisson-safe)
#define SELCAP 2048
#define SSTASH 0.9915f           // stash pre-filter; expected ~800 >= 512 (10 sigma)

// ws layout (bytes):
//   0:      u32 blk_cnt[256]       (1 KB)
//   1024:   u64 stash[256*64]      (128 KB)  ends 132096
//   132096: u64 gkeys[2048]        (16 KB)   ends 148480   (fallback only)
//   148480: u64 slots[512]         (4 KB)    ends 152576
//   152576: u64 supW[512*8]        (32 KB)   ends 185344
//   185344: u32 ghist[2048]        (8 KB)    ends 193536   (fallback only)
//   193536: u32 gcnt               (4 B)                   (fallback only)

__device__ __forceinline__ uint64_t pack_key(float s, int idx) {
    // descending score, ascending index tie-break (== stable top_k)
    return ((uint64_t)__float_as_uint(s) << 32) | (uint32_t)(~idx);
}

__device__ __forceinline__ float score_of(float c0, float c1) {
    #pragma clang fp contract(off)
    float m  = fmaxf(c0, c1);
    float e0 = expf(c0 - m);
    float e1 = expf(c1 - m);
    return e1 / (e0 + e1);
}

__device__ __forceinline__ int bin_of(float s) {
    #pragma clang fp contract(off)
    int b = (int)((s - 0.9f) * 20480.0f);   // 2048 bins over (0.9, 1.0]
    return b > (NBINS - 1) ? (NBINS - 1) : b;
}

__launch_bounds__(1024)
__global__ void fused(const float4* __restrict__ loc,
                      const float4* __restrict__ priors,
                      const float4* __restrict__ conf4,
                      uint32_t* __restrict__ blk_cnt,
                      uint64_t* __restrict__ stash,
                      uint64_t* __restrict__ gkeys,
                      uint64_t* __restrict__ slots,
                      uint64_t* __restrict__ supW,
                      uint32_t* __restrict__ ghist,
                      uint32_t* __restrict__ gcnt,
                      float* __restrict__ out) {
    #pragma clang fp contract(off)
    __shared__ uint64_t arena[4096];        // 32 KB: lkeys / hist / supLDS (aliased)
    __shared__ float4 bpk[KTOP];            // 8 KB pixel boxes
    __shared__ float  sar[KTOP], ssc[KTOP]; // 4 KB
    __shared__ uint32_t pcnt[256];          // 1 KB prefix workspace
    __shared__ uint64_t rowany8[8], keepw[8];
    __shared__ uint32_t sflags, lcnt;
    __shared__ int bmaxS;

    int tid = threadIdx.x;          // 1024 threads
    int blk = blockIdx.x;           // 256 blocks
    int lane = tid & 63, wv = tid >> 6;
    cg::grid_group grid = cg::this_grid();

    // ============ Phase A (all blocks): stream conf slice, stash ============
    if (tid == 0) { lcnt = 0u; sflags = 0u; bmaxS = 0; }
    __syncthreads();
    uint64_t* reg = stash + (size_t)blk * SCAP;
    #pragma unroll
    for (int i = 0; i < 4; ++i) {
        int f4i = blk * 4096 + i * 1024 + tid;
        float4 c = conf4[f4i];
        float s0 = score_of(c.x, c.y);
        float s1 = score_of(c.z, c.w);
        if (s0 > SSTASH) {
            uint32_t p = atomicAdd(&lcnt, 1u);
            if (p < SCAP) reg[p] = pack_key(s0, f4i * 2);
        }
        if (s1 > SSTASH) {
            uint32_t p = atomicAdd(&lcnt, 1u);
            if (p < SCAP) reg[p] = pack_key(s1, f4i * 2 + 1);
        }
    }
    __syncthreads();
    if (tid == 0) blk_cnt[blk] = (lcnt <= SCAP) ? lcnt : 0xFFFFFFFFu;

    grid.sync();                                                    // S0

    // ============ counts + prefix + fb detect (redundant per block) =========
    uint32_t craw = (tid < 256) ? blk_cnt[tid] : 0u;
    bool ovf = (tid < 256) && (craw == 0xFFFFFFFFu);
    uint32_t c_t = ovf ? 0u : craw;
    if (ovf) atomicOr(&sflags, 1u);
    if (tid < 256) pcnt[tid] = c_t;
    __syncthreads();
    for (int off = 1; off < 256; off <<= 1) {
        uint32_t v = 0; bool act = tid < 256;
        if (act) v = pcnt[tid] + ((tid >= off) ? pcnt[tid - off] : 0u);
        __syncthreads();
        if (act) pcnt[tid] = v;
        __syncthreads();
    }
    uint32_t n = pcnt[255];
    if (tid == 0 && (n < KTOP || n > SELCAP)) atomicOr(&sflags, 1u);
    __syncthreads();
    bool fb = (sflags != 0u);    // grid-uniform (same inputs everywhere)
    __syncthreads();

    uint64_t* lkeys = arena;
    if (!fb) {
        // gather own view of all stash entries into LDS
        if (tid < 256) {
            uint32_t base = pcnt[tid] - c_t;
            const uint64_t* regp = stash + (size_t)tid * SCAP;
            for (uint32_t j = 0; j < c_t; ++j) lkeys[base + j] = regp[j];
        }
        __syncthreads();
    } else {
        // ---------- exact fallback (cold): distributed histogram select -----
        if (tid < 8) ghist[blk * 8 + tid] = 0u;
        if (blk == 0 && tid == 0) gcnt[0] = 0u;
        grid.sync();                                                // S1a
        #pragma unroll
        for (int i = 0; i < 4; ++i) {
            int f4i = blk * 4096 + i * 1024 + tid;
            float4 c = conf4[f4i];
            float s0 = score_of(c.x, c.y);
            float s1 = score_of(c.z, c.w);
            if (s0 > 0.9f) atomicAdd(&ghist[bin_of(s0)], 1u);
            if (s1 > 0.9f) atomicAdd(&ghist[bin_of(s1)], 1u);
        }
        grid.sync();                                                // S1b
        // redundant per-block suffix scan of ghist in LDS
        uint32_t* hist = (uint32_t*)arena;
        hist[tid] = ghist[tid]; hist[tid + 1024] = ghist[tid + 1024];
        __syncthreads();
        for (int off = 1; off < NBINS; off <<= 1) {
            int b0 = tid, b1 = tid + 1024;
            uint32_t v0 = hist[b0] + ((b0 + off < NBINS) ? hist[b0 + off] : 0u);
            uint32_t v1 = hist[b1] + ((b1 + off < NBINS) ? hist[b1 + off] : 0u);
            __syncthreads();
            hist[b0] = v0; hist[b1] = v1;
            __syncthreads();
        }
        if (hist[tid] >= KTOP) atomicMax(&bmaxS, tid);
        if (hist[tid + 1024] >= KTOP) atomicMax(&bmaxS, tid + 1024);
        __syncthreads();
        int B = bmaxS;
        #pragma unroll
        for (int i = 0; i < 4; ++i) {
            int f4i = blk * 4096 + i * 1024 + tid;
            float4 c = conf4[f4i];
            float s0 = score_of(c.x, c.y);
            float s1 = score_of(c.z, c.w);
            if (s0 > 0.9f && bin_of(s0) >= B) {
                uint32_t p = atomicAdd(gcnt, 1u);
                if (p < SELCAP) gkeys[p] = pack_key(s0, 2 * f4i);
            }
            if (s1 > 0.9f && bin_of(s1) >= B) {
                uint32_t p = atomicAdd(gcnt, 1u);
                if (p < SELCAP) gkeys[p] = pack_key(s1, 2 * f4i + 1);
            }
        }
        grid.sync();                                                // S2
        n = gcnt[0]; if (n > SELCAP) n = SELCAP;
        __syncthreads();   // hist (arena) dead before lkeys overwrite
        for (uint32_t t = tid; t < n; t += 1024) lkeys[t] = gkeys[t];
        __syncthreads();
    }
    uint32_t nf = n < KTOP ? n : KTOP;

    // ============ rank phase: one wave per candidate, no barriers ===========
    {
        int c = blk * 16 + wv;      // covers 0..4095 >= n
        if ((uint32_t)c < n) {
            uint64_t K = lkeys[c];
            int cnt = 0;
            for (uint32_t j = lane; j < n; j += 64) cnt += (lkeys[j] > K) ? 1 : 0;
            #pragma unroll
            for (int m = 1; m < 64; m <<= 1) cnt += __shfl_xor(cnt, m);
            if (lane == 0 && cnt < KTOP) slots[cnt] = K;
        }
    }
    grid.sync();                                                    // S3

    // ============ decode (every block, redundant) + 2 matrix rows ===========
    if (tid < KTOP) {
        float4 bb; float area, sc;
        if ((uint32_t)tid < nf) {
            uint64_t key = slots[tid];
            sc = __uint_as_float((uint32_t)(key >> 32));
            int idx  = (int)(~(uint32_t)key);
            float4 l = loc[idx];
            float4 p = priors[idx];
            float cx = p.x + (l.x * 0.1f) * p.z;
            float cy = p.y + (l.y * 0.1f) * p.w;
            float w  = p.z * expf(l.z * 0.2f);
            float h  = p.w * expf(l.w * 0.2f);
            float x1 = cx - w * 0.5f;
            float y1 = cy - h * 0.5f;
            float x2 = x1 + w;
            float y2 = y1 + h;
            x1 *= 2048.0f; y1 *= 2048.0f; x2 *= 2048.0f; y2 *= 2048.0f;
            bb = make_float4(x1, y1, x2, y2);
            area = (x2 - x1 + 1.0f) * (y2 - y1 + 1.0f);
        } else {
            bb = make_float4(0.f, 0.f, 0.f, 0.f); area = 1.f; sc = 0.f;
        }
        bpk[tid] = bb; sar[tid] = area; ssc[tid] = sc;
    }
    __syncthreads();
    {
        int r   = 2 * blk + (tid >> 9);     // this block's two rows
        int col = tid & 511;
        float4 rb = bpk[r];  float ra = sar[r];
        float4 cb = bpk[col];
        float xx1 = fmaxf(rb.x, cb.x);
        float yy1 = fmaxf(rb.y, cb.y);
        float xx2 = fminf(rb.z, cb.z);
        float yy2 = fminf(rb.w, cb.w);
        float ww = fmaxf(xx2 - xx1 + 1.0f, 0.0f);
        float hh = fmaxf(yy2 - yy1 + 1.0f, 0.0f);
        float inter = ww * hh;
        float iou = inter / (ra + sar[col] - inter);
        uint64_t word = __ballot(iou > 0.4f && col > r);
        if (lane == 0) supW[r * 8 + ((tid >> 6) & 7)] = word;
    }
    grid.sync();                                                    // S4
    if (blk != 0) return;

    // ============ block 0: bitmask greedy scan + epilogue ===================
    uint64_t* supLDS = arena;   // lkeys dead
    for (int t = tid; t < 4096; t += 1024) supLDS[t] = supW[t];
    __syncthreads();
    if (tid < 512) {            // waves 0..7: rowany bit per row via ballot
        uint64_t a = 0ull;
        #pragma unroll
        for (int k = 0; k < 8; ++k) a |= supLDS[tid * 8 + k];
        uint64_t bal = __ballot(a != 0ull);
        if (lane == 0) rowany8[wv] = bal;
    }
    __syncthreads();

    if (tid == 0) {
        #define VAL64(c) ((nf >= (uint32_t)(((c)+1)*64)) ? ~0ull : \
            ((nf > (uint32_t)((c)*64)) ? ((1ull << (nf - (c)*64)) - 1ull) : 0ull))
        uint64_t kp0 = VAL64(0), kp1 = VAL64(1), kp2 = VAL64(2), kp3 = VAL64(3);
        uint64_t kp4 = VAL64(4), kp5 = VAL64(5), kp6 = VAL64(6), kp7 = VAL64(7);
        #define APPLYROW(i) do { const uint64_t* rp = supLDS + (size_t)(i) * 8; \
            kp0 &= ~rp[0]; kp1 &= ~rp[1]; kp2 &= ~rp[2]; kp3 &= ~rp[3]; \
            kp4 &= ~rp[4]; kp5 &= ~rp[5]; kp6 &= ~rp[6]; kp7 &= ~rp[7]; } while (0)
        #define CHUNK(c, KPC) do { uint64_t ra = rowany8[c]; uint64_t m = (KPC) & ra; \
            while (m) { int b = __builtin_ctzll(m); APPLYROW((c) * 64 + b); \
                uint64_t above = (b == 63) ? 0ull : (~0ull << (b + 1)); \
                m = (KPC) & ra & above; } } while (0)
        CHUNK(0, kp0); CHUNK(1, kp1); CHUNK(2, kp2); CHUNK(3, kp3);
        CHUNK(4, kp4); CHUNK(5, kp5); CHUNK(6, kp6); CHUNK(7, kp7);
        keepw[0] = kp0; keepw[1] = kp1; keepw[2] = kp2; keepw[3] = kp3;
        keepw[4] = kp4; keepw[5] = kp5; keepw[6] = kp6; keepw[7] = kp7;
        #undef CHUNK
        #undef APPLYROW
        #undef VAL64
    }
    __syncthreads();

    if (tid < KTOP) {
        const float inv = 1.0f / 2048.0f;   // exact pow2
        int kb = (int)((keepw[tid >> 6] >> (tid & 63)) & 1ull);
        float4 bb = bpk[tid];
        float* o = out + tid * 5;
        if (kb) {
            o[0] = bb.x * inv;
            o[1] = bb.y * inv;
            o[2] = bb.z * inv;
            o[3] = bb.w * inv;
            o[4] = ssc[tid];
        } else {
            o[0] = 0.f; o[1] = 0.f; o[2] = 0.f; o[3] = 0.f; o[4] = 0.f;
        }
    }
}

extern "C" void kernel_launch(void* const* d_in, const int* in_sizes, int n_in,
                              void* d_out, int out_size, void* d_ws, size_t ws_size,
                              hipStream_t stream) {
    const float4* loc4  = (const float4*)d_in[0];   // [1,N,4]
    const float4* conf4 = (const float4*)d_in[1];   // [1,N,2] as float4 pairs
    const float4* pri4  = (const float4*)d_in[2];   // [N,4]
    float* outp = (float*)d_out;                    // [512,5]

    uint8_t* ws = (uint8_t*)d_ws;
    uint32_t* blk_cnt = (uint32_t*)ws;               // 1 KB
    uint64_t* stash   = (uint64_t*)(ws + 1024);      // 128 KB
    uint64_t* gkeys   = (uint64_t*)(ws + 132096);    // 16 KB
    uint64_t* slots   = (uint64_t*)(ws + 148480);    // 4 KB
    uint64_t* supW    = (uint64_t*)(ws + 152576);    // 32 KB
    uint32_t* ghist   = (uint32_t*)(ws + 185344);    // 8 KB
    uint32_t* gcnt    = (uint32_t*)(ws + 193536);    // 4 B

    void* args[] = { (void*)&loc4, (void*)&pri4, (void*)&conf4,
                     (void*)&blk_cnt, (void*)&stash, (void*)&gkeys,
                     (void*)&slots, (void*)&supW, (void*)&ghist,
                     (void*)&gcnt, (void*)&outp };
    hipLaunchCooperativeKernel(reinterpret_cast<void*>(fused),
                               dim3(GBLK), dim3(1024), args, 0, stream);
}

// Round 9
// 182.984 us; speedup vs baseline: 1.2780x; 1.1408x over previous
//
#include <hip/hip_runtime.h>
#include <stdint.h>

// Problem constants (match reference)
#define N_PRIORS 2097152
#define KTOP 512
#define NBINS 2048
#define GBLK 256                 // cooperative grid: 1 block per CU
#define SCAP 64                  // LDS stage slots per block (mean 3.1, Poisson-safe)
#define SELCAP 2048
#define SSTASH 0.9915f           // pre-filter; expected ~800 >= 512 (10 sigma)

// ws layout (bytes):
//   0:     u32 ctr[16] (memset to 0): 0=S0 1=S1 2=S2 3=F0 4=F1 5=F2 6=gTotal 7=flags 8=gcnt2
//   128:   u64 dense[2048]   (16 KB)  ends 16512
//   16512: u64 slots[512]    (4 KB)   ends 20608
//   20608: u64 supW[512*8]   (32 KB)  ends 53376
//   53376: u32 ghist[2048]   (8 KB)   ends 61568   (fallback only)

__device__ __forceinline__ uint64_t pack_key(float s, int idx) {
    // descending score, ascending index tie-break (== stable top_k)
    return ((uint64_t)__float_as_uint(s) << 32) | (uint32_t)(~idx);
}

__device__ __forceinline__ float score_of(float c0, float c1) {
    #pragma clang fp contract(off)
    float m  = fmaxf(c0, c1);
    float e0 = expf(c0 - m);
    float e1 = expf(c1 - m);
    return e1 / (e0 + e1);
}

__device__ __forceinline__ int bin_of(float s) {
    #pragma clang fp contract(off)
    int b = (int)((s - 0.9f) * 20480.0f);   // 2048 bins over (0.9, 1.0]
    return b > (NBINS - 1) ? (NBINS - 1) : b;
}

// Lightweight grid barrier: device-scope arrive + tight relaxed-spin.
// (cg::grid.sync's coarse s_sleep backoff cost ~29us/sync at idle clock.)
__device__ __forceinline__ void gbar(uint32_t* c, bool wait) {
    __syncthreads();
    if (threadIdx.x == 0) {
        __threadfence();                     // release (agent scope)
        atomicAdd(c, 1u);                    // device-scope arrival
        if (wait) {
            while (__hip_atomic_load(c, __ATOMIC_RELAXED,
                                     __HIP_MEMORY_SCOPE_AGENT) < (uint32_t)GBLK)
                __builtin_amdgcn_s_sleep(1); // 64-cy naps, fine-grained
            __threadfence();                 // acquire: invalidate L1/XCD-L2
        }
    }
    __syncthreads();
}

__launch_bounds__(1024)
__global__ void fused(const float4* __restrict__ loc,
                      const float4* __restrict__ priors,
                      const float4* __restrict__ conf4,
                      uint32_t* __restrict__ ctr,
                      uint64_t* __restrict__ dense,
                      uint64_t* __restrict__ slots,
                      uint64_t* __restrict__ supW,
                      uint32_t* __restrict__ ghist,
                      float* __restrict__ out) {
    #pragma clang fp contract(off)
    __shared__ uint64_t arena[4096];        // 32 KB: fb-hist / blk0 supLDS (aliased)
    __shared__ float4 bpk[KTOP];            // 8 KB pixel boxes
    __shared__ float  sar[KTOP], ssc[KTOP]; // 4 KB
    __shared__ uint64_t stage[SCAP];        // 512 B local stash
    __shared__ uint64_t rowany8[8], keepw[8];
    __shared__ uint32_t lcnt, gbaseS, nS, flagsS;
    __shared__ int bmaxS;

    int tid = threadIdx.x;          // 1024 threads
    int blk = blockIdx.x;           // 256 blocks
    int lane = tid & 63, wv = tid >> 6;

    // ============ Phase A: stream conf slice, stage > SSTASH in LDS =========
    if (tid == 0) { lcnt = 0u; bmaxS = 0; }
    __syncthreads();
    #pragma unroll
    for (int i = 0; i < 4; ++i) {
        int f4i = blk * 4096 + i * 1024 + tid;
        float4 c = conf4[f4i];
        float s0 = score_of(c.x, c.y);
        float s1 = score_of(c.z, c.w);
        if (s0 > SSTASH) {
            uint32_t p = atomicAdd(&lcnt, 1u);
            if (p < SCAP) stage[p] = pack_key(s0, 2 * f4i);
        }
        if (s1 > SSTASH) {
            uint32_t p = atomicAdd(&lcnt, 1u);
            if (p < SCAP) stage[p] = pack_key(s1, 2 * f4i + 1);
        }
    }
    __syncthreads();
    uint32_t c_blk = (lcnt <= SCAP) ? lcnt : SCAP;
    if (tid == 0) {
        if (lcnt > SCAP) atomicOr(&ctr[7], 1u);
        gbaseS = atomicAdd(&ctr[6], c_blk);   // one global atomic per block
    }
    __syncthreads();
    if (tid < c_blk && gbaseS + tid < SELCAP) dense[gbaseS + tid] = stage[tid];

    gbar(&ctr[0], true);                                            // S0

    if (tid == 0) {
        nS = __hip_atomic_load(&ctr[6], __ATOMIC_RELAXED, __HIP_MEMORY_SCOPE_AGENT);
        flagsS = __hip_atomic_load(&ctr[7], __ATOMIC_RELAXED, __HIP_MEMORY_SCOPE_AGENT);
    }
    __syncthreads();
    uint32_t n = nS;
    bool fb = (flagsS != 0u) || (n < KTOP) || (n > SELCAP);   // grid-uniform

    if (fb) {
        // ---------- exact fallback (cold): distributed histogram select -----
        if (tid < 8) ghist[blk * 8 + tid] = 0u;
        gbar(&ctr[3], true);                                        // F0
        #pragma unroll
        for (int i = 0; i < 4; ++i) {
            int f4i = blk * 4096 + i * 1024 + tid;
            float4 c = conf4[f4i];
            float s0 = score_of(c.x, c.y);
            float s1 = score_of(c.z, c.w);
            if (s0 > 0.9f) atomicAdd(&ghist[bin_of(s0)], 1u);
            if (s1 > 0.9f) atomicAdd(&ghist[bin_of(s1)], 1u);
        }
        gbar(&ctr[4], true);                                        // F1
        uint32_t* hist = (uint32_t*)arena;   // redundant per-block suffix scan
        hist[tid] = ghist[tid]; hist[tid + 1024] = ghist[tid + 1024];
        __syncthreads();
        for (int off = 1; off < NBINS; off <<= 1) {
            int b0 = tid, b1 = tid + 1024;
            uint32_t v0 = hist[b0] + ((b0 + off < NBINS) ? hist[b0 + off] : 0u);
            uint32_t v1 = hist[b1] + ((b1 + off < NBINS) ? hist[b1 + off] : 0u);
            __syncthreads();
            hist[b0] = v0; hist[b1] = v1;
            __syncthreads();
        }
        if (hist[tid] >= KTOP) atomicMax(&bmaxS, tid);
        if (hist[tid + 1024] >= KTOP) atomicMax(&bmaxS, tid + 1024);
        __syncthreads();
        int B = bmaxS;
        #pragma unroll
        for (int i = 0; i < 4; ++i) {
            int f4i = blk * 4096 + i * 1024 + tid;
            float4 c = conf4[f4i];
            float s0 = score_of(c.x, c.y);
            float s1 = score_of(c.z, c.w);
            if (s0 > 0.9f && bin_of(s0) >= B) {
                uint32_t p = atomicAdd(&ctr[8], 1u);
                if (p < SELCAP) dense[p] = pack_key(s0, 2 * f4i);
            }
            if (s1 > 0.9f && bin_of(s1) >= B) {
                uint32_t p = atomicAdd(&ctr[8], 1u);
                if (p < SELCAP) dense[p] = pack_key(s1, 2 * f4i + 1);
            }
        }
        gbar(&ctr[5], true);                                        // F2
        if (tid == 0)
            nS = __hip_atomic_load(&ctr[8], __ATOMIC_RELAXED, __HIP_MEMORY_SCOPE_AGENT);
        __syncthreads();
        n = nS; if (n > SELCAP) n = SELCAP;
    }
    uint32_t nf = n < KTOP ? n : KTOP;

    // ============ rank phase: one wave per candidate, no block barriers =====
    {
        int cidx = blk * 16 + wv;           // covers 0..4095 >= n
        if ((uint32_t)cidx < n) {
            uint64_t K = dense[cidx];
            int cnt = 0;
            for (uint32_t j = lane; j < n; j += 64) cnt += (dense[j] > K) ? 1 : 0;
            #pragma unroll
            for (int m = 1; m < 64; m <<= 1) cnt += __shfl_xor(cnt, m);
            if (lane == 0 && cnt < KTOP) slots[cnt] = K;   // ranks are distinct
        }
    }
    gbar(&ctr[1], true);                                            // S1

    // ============ decode (every block, redundant) + 2 matrix rows ===========
    if (tid < KTOP) {
        float4 bb; float area, sc;
        if ((uint32_t)tid < nf) {
            uint64_t key = slots[tid];
            sc = __uint_as_float((uint32_t)(key >> 32));
            int idx  = (int)(~(uint32_t)key);
            float4 l = loc[idx];
            float4 p = priors[idx];
            float cx = p.x + (l.x * 0.1f) * p.z;
            float cy = p.y + (l.y * 0.1f) * p.w;
            float w  = p.z * expf(l.z * 0.2f);
            float h  = p.w * expf(l.w * 0.2f);
            float x1 = cx - w * 0.5f;
            float y1 = cy - h * 0.5f;
            float x2 = x1 + w;
            float y2 = y1 + h;
            x1 *= 2048.0f; y1 *= 2048.0f; x2 *= 2048.0f; y2 *= 2048.0f;
            bb = make_float4(x1, y1, x2, y2);
            area = (x2 - x1 + 1.0f) * (y2 - y1 + 1.0f);
        } else {
            bb = make_float4(0.f, 0.f, 0.f, 0.f); area = 1.f; sc = 0.f;
        }
        bpk[tid] = bb; sar[tid] = area; ssc[tid] = sc;
    }
    __syncthreads();
    {
        int r   = 2 * blk + (tid >> 9);     // this block's two rows
        int col = tid & 511;
        float4 rb = bpk[r];  float ra = sar[r];
        float4 cb = bpk[col];
        float xx1 = fmaxf(rb.x, cb.x);
        float yy1 = fmaxf(rb.y, cb.y);
        float xx2 = fminf(rb.z, cb.z);
        float yy2 = fminf(rb.w, cb.w);
        float ww = fmaxf(xx2 - xx1 + 1.0f, 0.0f);
        float hh = fmaxf(yy2 - yy1 + 1.0f, 0.0f);
        float inter = ww * hh;
        float iou = inter / (ra + sar[col] - inter);
        uint64_t word = __ballot(iou > 0.4f && col > r);
        if (lane == 0) supW[r * 8 + ((tid >> 6) & 7)] = word;
    }
    gbar(&ctr[2], blk == 0);                // S2: others arrive-and-exit
    if (blk != 0) return;

    // ============ block 0: bitmask greedy scan + epilogue ===================
    uint64_t* supLDS = arena;
    for (int t = tid; t < 4096; t += 1024) supLDS[t] = supW[t];
    __syncthreads();
    if (tid < 512) {            // waves 0..7: rowany bit per row via ballot
        uint64_t a = 0ull;
        #pragma unroll
        for (int k = 0; k < 8; ++k) a |= supLDS[tid * 8 + k];
        uint64_t bal = __ballot(a != 0ull);
        if (lane == 0) rowany8[wv] = bal;
    }
    __syncthreads();

    if (tid == 0) {
        #define VAL64(c) ((nf >= (uint32_t)(((c)+1)*64)) ? ~0ull : \
            ((nf > (uint32_t)((c)*64)) ? ((1ull << (nf - (c)*64)) - 1ull) : 0ull))
        uint64_t kp0 = VAL64(0), kp1 = VAL64(1), kp2 = VAL64(2), kp3 = VAL64(3);
        uint64_t kp4 = VAL64(4), kp5 = VAL64(5), kp6 = VAL64(6), kp7 = VAL64(7);
        #define APPLYROW(i) do { const uint64_t* rp = supLDS + (size_t)(i) * 8; \
            kp0 &= ~rp[0]; kp1 &= ~rp[1]; kp2 &= ~rp[2]; kp3 &= ~rp[3]; \
            kp4 &= ~rp[4]; kp5 &= ~rp[5]; kp6 &= ~rp[6]; kp7 &= ~rp[7]; } while (0)
        #define CHUNK(c, KPC) do { uint64_t ra = rowany8[c]; uint64_t m = (KPC) & ra; \
            while (m) { int b = __builtin_ctzll(m); APPLYROW((c) * 64 + b); \
                uint64_t above = (b == 63) ? 0ull : (~0ull << (b + 1)); \
                m = (KPC) & ra & above; } } while (0)
        CHUNK(0, kp0); CHUNK(1, kp1); CHUNK(2, kp2); CHUNK(3, kp3);
        CHUNK(4, kp4); CHUNK(5, kp5); CHUNK(6, kp6); CHUNK(7, kp7);
        keepw[0] = kp0; keepw[1] = kp1; keepw[2] = kp2; keepw[3] = kp3;
        keepw[4] = kp4; keepw[5] = kp5; keepw[6] = kp6; keepw[7] = kp7;
        #undef CHUNK
        #undef APPLYROW
        #undef VAL64
    }
    __syncthreads();

    if (tid < KTOP) {
        const float inv = 1.0f / 2048.0f;   // exact pow2
        int kb = (int)((keepw[tid >> 6] >> (tid & 63)) & 1ull);
        float4 bb = bpk[tid];
        float* o = out + tid * 5;
        if (kb) {
            o[0] = bb.x * inv;
            o[1] = bb.y * inv;
            o[2] = bb.z * inv;
            o[3] = bb.w * inv;
            o[4] = ssc[tid];
        } else {
            o[0] = 0.f; o[1] = 0.f; o[2] = 0.f; o[3] = 0.f; o[4] = 0.f;
        }
    }
}

extern "C" void kernel_launch(void* const* d_in, const int* in_sizes, int n_in,
                              void* d_out, int out_size, void* d_ws, size_t ws_size,
                              hipStream_t stream) {
    const float4* loc4  = (const float4*)d_in[0];   // [1,N,4]
    const float4* conf4 = (const float4*)d_in[1];   // [1,N,2] as float4 pairs
    const float4* pri4  = (const float4*)d_in[2];   // [N,4]
    float* outp = (float*)d_out;                    // [512,5]

    uint8_t* ws = (uint8_t*)d_ws;
    uint32_t* ctr   = (uint32_t*)ws;                // 64 B (zeroed below)
    uint64_t* dense = (uint64_t*)(ws + 128);        // 16 KB
    uint64_t* slots = (uint64_t*)(ws + 16512);      // 4 KB
    uint64_t* supW  = (uint64_t*)(ws + 20608);      // 32 KB
    uint32_t* ghist = (uint32_t*)(ws + 53376);      // 8 KB

    hipMemsetAsync(ws, 0, 64, stream);              // barrier counters + totals

    void* args[] = { (void*)&loc4, (void*)&pri4, (void*)&conf4,
                     (void*)&ctr, (void*)&dense, (void*)&slots,
                     (void*)&supW, (void*)&ghist, (void*)&outp };
    hipLaunchCooperativeKernel(reinterpret_cast<void*>(fused),
                               dim3(GBLK), dim3(1024), args, 0, stream);
}